// Round 1
// baseline (916.467 us; speedup 1.0000x reference)
//
#include <hip/hip_runtime.h>
#include <math.h>

#define N_TOTAL    68096
#define NUM_INPUT  2048
#define NUM_HIDDEN 65536
#define NUM_OUTPUT 512
#define OUT_START  67584   // NUM_INPUT + NUM_HIDDEN
#define FAN_OUT    256
#define THRESH     0.3f
#define T_MAX      50

// ---------------------------------------------------------------------------
// Input-spike dtype detection: bool array may arrive as int32{0,1},
// float32{0.0,1.0}, or packed uint8{0,1}. Scan first 512 words (2048 bytes,
// safe under all encodings):
//   - words == 0x3F800000 (1.0f) appear only in FLOAT mode  -> mode 1
//   - else any word > 1 only possible with packed bytes      -> mode 2
//   - else int32                                             -> mode 0
// ---------------------------------------------------------------------------
__global__ void detect_mode_k(const unsigned int* in0, int* mode) {
    __shared__ int cntF, anyG;
    if (threadIdx.x == 0) { cntF = 0; anyG = 0; }
    __syncthreads();
    unsigned int v = in0[threadIdx.x];          // 512 threads
    if (v == 0x3F800000u) atomicAdd(&cntF, 1);
    else if (v > 1u)      atomicOr(&anyG, 1);
    __syncthreads();
    if (threadIdx.x == 0) *mode = (cntF >= 8) ? 1 : (anyG ? 2 : 0);
}

__global__ __launch_bounds__(256) void init_k(
    const void* in0, const int* mode_p,
    float* pot, float* acc, int* last_up, int* touch, unsigned char* fired,
    int* frontier0, int* cnt, float* out_times, float* decay_tab)
{
    int i = blockIdx.x * blockDim.x + threadIdx.x;
    int mode = *mode_p;
    if (i <= T_MAX) {
        // mirror: decay_base = exp(f32(-1/20)); decay_base ** dt
        float base = expf(-0.05f);
        decay_tab[i] = (float)pow((double)base, (double)i);
    }
    if (i < NUM_OUTPUT) out_times[i] = -1.0f;
    if (i < N_TOTAL) {
        pot[i] = 0.0f;
        acc[i] = 0.0f;
        last_up[i] = 0;
        touch[i] = -1;
        bool s = false;
        if (i < NUM_INPUT) {
            if (mode == 0)      s = ((const int*)in0)[i] != 0;
            else if (mode == 1) s = ((const float*)in0)[i] != 0.0f;
            else                s = ((const unsigned char*)in0)[i] != 0;
        }
        fired[i] = s ? 1 : 0;
        if (s) {
            int p = atomicAdd(&cnt[0], 1);
            frontier0[p] = i;
        }
    }
}

// K1: deliver spikes of this step's frontier. acc += strength*w, mark touch=t.
__global__ __launch_bounds__(256) void scatter_k(
    const int* __restrict__ frontier, const int* __restrict__ cnt_cur,
    int* cnt_next,
    const int* __restrict__ targets, const float* __restrict__ weights,
    float* __restrict__ acc, int* __restrict__ touch, int t)
{
    if (blockIdx.x == 0 && threadIdx.x == 0) *cnt_next = 0; // consumed last step
    int total  = (*cnt_cur) * FAN_OUT;
    int stride = gridDim.x * blockDim.x;
    for (int idx = blockIdx.x * blockDim.x + threadIdx.x; idx < total; idx += stride) {
        int   s  = frontier[idx >> 8];
        int   j  = idx & (FAN_OUT - 1);
        int   tg = targets[s * FAN_OUT + j];
        float w  = weights[s * FAN_OUT + j];
        float st = (s < NUM_INPUT) ? 2.0f : 1.0f;
        atomicAdd(&acc[tg], st * w);
        touch[tg] = t;   // racy same-value store: fine
    }
}

// K2: for touched neurons: lazy decay, integrate, spike check, reset, schedule.
__global__ __launch_bounds__(256) void update_k(
    float* __restrict__ pot, float* __restrict__ acc,
    int* __restrict__ last_up, const int* __restrict__ touch,
    unsigned char* __restrict__ fired,
    int* __restrict__ frontier_next, int* __restrict__ cnt_next,
    float* __restrict__ out_times, const float* __restrict__ decay_tab, int t)
{
    int i = blockIdx.x * blockDim.x + threadIdx.x;
    if (i >= N_TOTAL) return;
    if (touch[i] != t) return;
    float p = pot[i] * decay_tab[t - last_up[i]] + acc[i];
    acc[i] = 0.0f;
    last_up[i] = t;
    if (!fired[i] && p >= THRESH) {
        fired[i] = 1;
        if (i < OUT_START) {
            p = 0.0f;                       // reset non-output membrane
            int pos = atomicAdd(cnt_next, 1);
            frontier_next[pos] = i;         // deliver at t+1
        } else {
            out_times[i - OUT_START] = (float)t;  // first (only) fire
        }
    }
    pot[i] = p;
}

__global__ void final_k(const float* __restrict__ pot,
                        const int* __restrict__ last_up,
                        const float* __restrict__ decay_tab,
                        float* __restrict__ out_pot)
{
    int i = blockIdx.x * blockDim.x + threadIdx.x;
    if (i < NUM_OUTPUT) {
        int n = OUT_START + i;
        out_pot[i] = pot[n] * decay_tab[T_MAX - last_up[n]];
    }
}

extern "C" void kernel_launch(void* const* d_in, const int* in_sizes, int n_in,
                              void* d_out, int out_size, void* d_ws, size_t ws_size,
                              hipStream_t stream) {
    const void*  in_spikes = d_in[0];
    const float* weights   = (const float*)d_in[1];
    const int*   targets   = (const int*)d_in[2];
    // d_in[3] = max_timesteps (== 50, fixed by setup_inputs)

    float* out_f = (float*)d_out;          // [0..511] times, [512..1023] pot

    // -------- workspace carve (needs ~1.71 MB) --------
    char* w = (char*)d_ws;
    int*   cnt       = (int*)w;                      // cnt[0], cnt[1]
    int*   mode      = (int*)(w + 16);
    float* decay_tab = (float*)(w + 256);            // 64 floats
    float* pot       = (float*)(w + 512);
    float* acc       = pot + N_TOTAL;
    int*   last_up   = (int*)(acc + N_TOTAL);
    int*   touch     = last_up + N_TOTAL;
    int*   fr0       = touch + N_TOTAL;
    int*   fr1       = fr0 + N_TOTAL;
    unsigned char* fired = (unsigned char*)(fr1 + N_TOTAL);

    hipMemsetAsync(cnt, 0, 8, stream);
    detect_mode_k<<<1, 512, 0, stream>>>((const unsigned int*)in_spikes, mode);

    int nblk = (N_TOTAL + 255) / 256;
    init_k<<<nblk, 256, 0, stream>>>(in_spikes, mode, pot, acc, last_up, touch,
                                     fired, fr0, cnt, out_f, decay_tab);

    int* fr[2] = {fr0, fr1};
    int cur = 0;
    for (int t = 0; t < T_MAX; ++t) {
        scatter_k<<<512, 256, 0, stream>>>(fr[cur], &cnt[cur], &cnt[1 - cur],
                                           targets, weights, acc, touch, t);
        update_k<<<nblk, 256, 0, stream>>>(pot, acc, last_up, touch, fired,
                                           fr[1 - cur], &cnt[1 - cur],
                                           out_f, decay_tab, t);
        cur ^= 1;
    }
    final_k<<<2, 256, 0, stream>>>(pot, last_up, decay_tab, out_f + NUM_OUTPUT);
}